// Round 1
// 145.806 us; speedup vs baseline: 1.0118x; 1.0118x over previous
//
#include <hip/hip_runtime.h>
#include <math.h>

#define T_STEPS 64
#define D_OUT 256

// One block (= one wave, 64 lanes) per (n,c); lane l computes 4 consecutive
// output channels j = 4l..4l+3 and stores them as one float4 (16 B/lane).
// x[:, nc, :] staged to LDS; delay/stochastic-rounding path kept in fp64 to
// match the float64 numpy reference bit-for-bit on the noise<frac threshold.
__global__ __launch_bounds__(64) void jeffress_kernel(
    const float* __restrict__ x,          // (T, NC, 2)
    const float* __restrict__ log_delay,  // (D_OUT)
    const float* __restrict__ log_weight, // (1)
    const float* __restrict__ noise,      // (NC, D_OUT, 2)
    float* __restrict__ out,              // (T, NC, D_OUT)
    int NC)
{
    __shared__ float xs0[T_STEPS];
    __shared__ float xs1[T_STEPS];

    const int nc = blockIdx.x;
    const int l  = threadIdx.x;        // 0..63
    const int j0 = l << 2;             // first of 4 output channels

    // ---- stage x[:, nc, :] into LDS: lane l loads timestep t=l (float2) ----
    const float2 xv = *(const float2*)(x + ((size_t)l * NC + nc) * 2);
    xs0[l] = xv.x;
    xs1[l] = xv.y;

    // ---- wave-parallel first-occurrence argmax over time, both channels ----
    // butterfly: keep larger value; on exact tie keep smaller index
    float v0 = xv.x, v1 = xv.y;
    int   i0 = l,    i1 = l;
    #pragma unroll
    for (int off = 1; off < 64; off <<= 1) {
        float ov0 = __shfl_xor(v0, off);
        int   oi0 = __shfl_xor(i0, off);
        float ov1 = __shfl_xor(v1, off);
        int   oi1 = __shfl_xor(i1, off);
        if (ov0 > v0 || (ov0 == v0 && oi0 < i0)) { v0 = ov0; i0 = oi0; }
        if (ov1 > v1 || (ov1 == v1 && oi1 < i1)) { v1 = ov1; i1 = oi1; }
    }
    const int maxd0 = (T_STEPS - 1) - i0;
    const int maxd1 = (T_STEPS - 1) - i1;

    // ---- per-j delay + stochastic rounding (double precision, as before) ----
    const float4 ldf = *(const float4*)(log_delay + j0);               // j0..j0+3
    const float4 ldr = *(const float4*)(log_delay + (D_OUT - 4 - j0)); // 252-j0..255-j0
    const float4 nA  = *(const float4*)(noise + ((size_t)nc * D_OUT + j0) * 2);
    const float4 nB  = *(const float4*)(noise + ((size_t)nc * D_OUT + j0) * 2 + 4);

    const float ld0[4] = { ldf.x, ldf.y, ldf.z, ldf.w };
    const float ld1[4] = { ldr.w, ldr.z, ldr.y, ldr.x };   // flipped channel
    const float n0[4]  = { nA.x, nA.z, nB.x, nB.z };
    const float n1[4]  = { nA.y, nA.w, nB.y, nB.w };

    int rd0[4], rd1[4];
    #pragma unroll
    for (int k = 0; k < 4; ++k) {
        double s0 = (double)T_STEPS * exp((double)ld0[k]);
        double s1 = (double)T_STEPS * exp((double)ld1[k]);
        double f0 = floor(s0), f1 = floor(s1);
        int r0 = (int)f0 + (((double)n0[k] < (s0 - f0)) ? 1 : 0);
        int r1 = (int)f1 + (((double)n1[k] < (s1 - f1)) ? 1 : 0);
        rd0[k] = min(r0, maxd0);   // 0 <= rd <= 63
        rd1[k] = min(r1, maxd1);
    }

    const float w = (float)exp((double)log_weight[0]);

    __syncthreads();

    // ---- leaky integrator over circularly-shifted x; float4 stores ----
    float y0[4] = {0.f, 0.f, 0.f, 0.f};
    float y1[4] = {0.f, 0.f, 0.f, 0.f};
    float* op = out + (size_t)nc * D_OUT + j0;
    const size_t ostride = (size_t)NC * D_OUT;

    #pragma unroll
    for (int t = 0; t < T_STEPS; ++t) {
        float4 o;
        #pragma unroll
        for (int k = 0; k < 4; ++k) {
            y0[k] = y0[k] * 0.5f + xs0[(t - rd0[k]) & (T_STEPS - 1)];
            y1[k] = y1[k] * 0.5f + xs1[(t - rd1[k]) & (T_STEPS - 1)];
            (&o.x)[k] = (y0[k] + y1[k]) * w;
        }
        *(float4*)(op + (size_t)t * ostride) = o;
    }
}

extern "C" void kernel_launch(void* const* d_in, const int* in_sizes, int n_in,
                              void* d_out, int out_size, void* d_ws, size_t ws_size,
                              hipStream_t stream) {
    const float* x          = (const float*)d_in[0];
    const float* log_delay  = (const float*)d_in[1];
    const float* log_weight = (const float*)d_in[2];
    const float* noise      = (const float*)d_in[3];
    float* out = (float*)d_out;

    const int NC = in_sizes[3] / (D_OUT * 2);  // noise = (N,C,D_OUT,2)

    jeffress_kernel<<<NC, T_STEPS, 0, stream>>>(x, log_delay, log_weight, noise, out, NC);
}